// Round 5
// baseline (182.433 us; speedup 1.0000x reference)
//
#include <hip/hip_runtime.h>
#include <hip/hip_bf16.h>

// Problem constants
#define NUM_NODES 500000
#define DD  128
#define UU  32
#define TT  4
#define AA  32
#define NSRC 65536
#define BB  8192
#define EE  262144                  // = 2^18
#define NEDGE (TT * EE)             // 2^20
#define NBKT (BB * TT)              // 32768 buckets, id = dst*4 + t
#define AGG_FLOATS (BB * TT * UU)   // 1,048,576 floats = 4 MB
#define NB  16                      // output nodes per block in node_kernel

// ---------------- compact gather domain: feats[src] = nte[input_nodes[src]]
__global__ __launch_bounds__(256) void feats_kernel(
    const float4* __restrict__ nte4,         // [NUM_NODES][32] float4
    const int* __restrict__ input_nodes,     // [NSRC]
    float4* __restrict__ feats4)             // [NSRC][32] float4
{
    int gtid = blockIdx.x * 256 + threadIdx.x;   // 0 .. NSRC*32-1
    int src = gtid >> 5, q = gtid & 31;
    long node = input_nodes[src];
    feats4[(long)src * 32 + q] = nte4[node * 32 + q];
}

// ---------------- zero int counters ----------------
__global__ __launch_bounds__(256) void zero_cnt_kernel(int4* __restrict__ p) {
    int i = blockIdx.x * 256 + threadIdx.x;   // covers NBKT/4 = 8192
    p[i] = make_int4(0, 0, 0, 0);
}

// ---------------- zero agg (fallback path) ----------------
__global__ __launch_bounds__(256) void zero_agg_kernel(float4* __restrict__ p) {
    int i = blockIdx.x * 256 + threadIdx.x;
    p[i] = make_float4(0.f, 0.f, 0.f, 0.f);
}

// ---------------- histogram of (dst,t) ----------------
__global__ __launch_bounds__(256) void hist_kernel(
    const int* __restrict__ edge_dst, int* __restrict__ cnt)
{
    int i = blockIdx.x * 256 + threadIdx.x;   // edge id in [0, NEDGE)
    int t = i >> 18;                           // E = 2^18
    int dst = edge_dst[i];
    atomicAdd(&cnt[dst * 4 + t], 1);
}

// ---------------- single-block exclusive scan of 32768 counters ----------
__global__ __launch_bounds__(1024) void scan_kernel(
    const int* __restrict__ cnt, int* __restrict__ base, int* __restrict__ cursor)
{
    __shared__ int partial[1024];
    int tid = threadIdx.x;
    int4 v[8];
    const int4* c4 = (const int4*)cnt + tid * 8;
    int s = 0;
    #pragma unroll
    for (int i = 0; i < 8; ++i) {
        v[i] = c4[i];
        s += v[i].x + v[i].y + v[i].z + v[i].w;
    }
    partial[tid] = s;
    __syncthreads();
    for (int off = 1; off < 1024; off <<= 1) {
        int add = (tid >= off) ? partial[tid - off] : 0;
        __syncthreads();
        partial[tid] += add;
        __syncthreads();
    }
    int run = (tid > 0) ? partial[tid - 1] : 0;
    #pragma unroll
    for (int i = 0; i < 8; ++i) {
        int4 b;
        b.x = run; run += v[i].x;
        b.y = run; run += v[i].y;
        b.z = run; run += v[i].z;
        b.w = run; run += v[i].w;
        ((int4*)base)[tid * 8 + i]   = b;
        ((int4*)cursor)[tid * 8 + i] = b;
    }
}

// ---------------- scatter edges into buckets (store src id) --------------
__global__ __launch_bounds__(256) void scatter_kernel(
    const int* __restrict__ edge_src,
    const int* __restrict__ edge_dst,
    int* __restrict__ cursor,
    int* __restrict__ sortedSrc)
{
    int i = blockIdx.x * 256 + threadIdx.x;
    int t = i >> 18;
    int dst = edge_dst[i];
    int pos = atomicAdd(&cursor[dst * 4 + t], 1);
    sortedSrc[pos] = edge_src[i];
}

// ---------------- gather: one wave per bucket, 8 edges/instr -------------
__global__ __launch_bounds__(256) void gather_kernel(
    const float4* __restrict__ feats4,     // [NSRC][32] float4
    const int* __restrict__ sortedSrc,
    const int* __restrict__ base,
    const int* __restrict__ cnt,
    float4* __restrict__ agg4)             // [B][T][8] float4
{
    int wv = threadIdx.x >> 6, lane = threadIdx.x & 63;
    int k = blockIdx.x * 4 + wv;           // bucket = dst*4 + t
    int t = k & 3, dst = k >> 2;
    int start = base[k], n = cnt[k];
    int e8 = lane >> 3, q = lane & 7;      // edge slot, float4 idx in row
    const float4* fp = feats4 + t * 8 + q;
    float4 acc = make_float4(0.f, 0.f, 0.f, 0.f);
    int j = e8;
    for (; j + 8 < n; j += 16) {
        int s0 = sortedSrc[start + j];
        int s1 = sortedSrc[start + j + 8];
        float4 v0 = fp[(long)s0 * 32];
        float4 v1 = fp[(long)s1 * 32];
        acc.x += v0.x + v1.x; acc.y += v0.y + v1.y;
        acc.z += v0.z + v1.z; acc.w += v0.w + v1.w;
    }
    if (j < n) {
        int s0 = sortedSrc[start + j];
        float4 v0 = fp[(long)s0 * 32];
        acc.x += v0.x; acc.y += v0.y; acc.z += v0.z; acc.w += v0.w;
    }
    #pragma unroll
    for (int m = 8; m < 64; m <<= 1) {
        acc.x += __shfl_xor(acc.x, m, 64);
        acc.y += __shfl_xor(acc.y, m, 64);
        acc.z += __shfl_xor(acc.z, m, 64);
        acc.w += __shfl_xor(acc.w, m, 64);
    }
    if (lane < 8) agg4[k * 8 + lane] = acc;
}

// ---------------- fallback: direct atomic scatter ------------------------
__global__ __launch_bounds__(256) void edge_atomic_kernel(
    const float* __restrict__ nte_in,
    const int* __restrict__ input_nodes,
    const int* __restrict__ edge_src,
    const int* __restrict__ edge_dst,
    float* __restrict__ agg)
{
    int tid = blockIdx.x * 256 + threadIdx.x;
    int i = tid >> 5;
    int u = tid & 31;
    int t = i >> 18;
    int src = edge_src[i];
    int dst = edge_dst[i];
    int node = input_nodes[src];
    float v = nte_in[(long)node * 128 + t * 32 + u];
    atomicAdd(&agg[dst * 128 + t * 32 + u], v);
}

// ---------------- per-output-node attention + transform ------------------
__global__ __launch_bounds__(256) void node_kernel(
    const float* __restrict__ node_emb,          // [NUM_NODES][D]
    const float* __restrict__ w,                 // [T][U][D]
    const float* __restrict__ s1,                // [T][U][A]
    const float* __restrict__ s2,                // [T][A]
    const int* __restrict__ output_nodes,        // [B]
    const float* __restrict__ agg,               // [B][T][U]
    float* __restrict__ out)                     // [B][T][D]
{
    __shared__ float s_nte[NB][TT * UU];
    __shared__ float s_comb[NB][UU];
    __shared__ float s_sc[NB][TT];
    __shared__ int   s_node[NB];

    int tid  = threadIdx.x;
    int wv   = tid >> 6;
    int lane = tid & 63;
    int b0   = blockIdx.x * NB;

    {
        const float4* av = (const float4*)(agg + b0 * 128);
        float4* sv = (float4*)&s_nte[0][0];
        sv[tid]       = av[tid];
        sv[tid + 256] = av[tid + 256];
    }
    if (tid < NB) s_node[tid] = output_nodes[b0 + tid];
    __syncthreads();

    // ---- Phase A: attention scores ----
    int a  = lane & 31;
    int th = lane >> 5;
    int t0 = th, t1 = th + 2;
    float s1a[UU], s1b[UU];
    #pragma unroll
    for (int u = 0; u < UU; ++u) {
        s1a[u] = s1[(t0 * UU + u) * AA + a];
        s1b[u] = s1[(t1 * UU + u) * AA + a];
    }
    float s2a = s2[t0 * AA + a];
    float s2b = s2[t1 * AA + a];

    #pragma unroll
    for (int q = 0; q < 4; ++q) {
        int bl = wv * 4 + q;
        float acc0 = 0.f, acc1 = 0.f;
        #pragma unroll
        for (int u = 0; u < UU; ++u) {
            acc0 += s_nte[bl][t0 * UU + u] * s1a[u];
            acc1 += s_nte[bl][t1 * UU + u] * s1b[u];
        }
        float p0 = tanhf(acc0) * s2a;
        float p1 = tanhf(acc1) * s2b;
        #pragma unroll
        for (int m = 1; m < 32; m <<= 1) {
            p0 += __shfl_xor(p0, m, 64);
            p1 += __shfl_xor(p1, m, 64);
        }
        if ((lane & 31) == 0) { s_sc[bl][th] = p0; s_sc[bl][th + 2] = p1; }
    }
    __syncthreads();

    #pragma unroll
    for (int q = 0; q < 4; ++q) {
        int bl = wv * 4 + q;
        float sc0 = s_sc[bl][0], sc1 = s_sc[bl][1];
        float sc2 = s_sc[bl][2], sc3 = s_sc[bl][3];
        float mx = fmaxf(fmaxf(sc0, sc1), fmaxf(sc2, sc3));
        float e0 = expf(sc0 - mx), e1 = expf(sc1 - mx);
        float e2 = expf(sc2 - mx), e3 = expf(sc3 - mx);
        float isum = 1.f / (e0 + e1 + e2 + e3);
        if (lane < 32) {
            float c = e0 * isum * s_nte[bl][a]
                    + e1 * isum * s_nte[bl][UU + a]
                    + e2 * isum * s_nte[bl][2 * UU + a]
                    + e3 * isum * s_nte[bl][3 * UU + a];
            s_comb[bl][a] = c;
        }
    }
    __syncthreads();

    // ---- Phase B: transform + add emb + normalize; wave == t ----
    int t = wv;
    const float* wt = w + t * (UU * DD);
    float wA[UU], wB[UU];
    #pragma unroll
    for (int u = 0; u < UU; ++u) {
        wA[u] = wt[u * DD + lane];
        wB[u] = wt[u * DD + lane + 64];
    }
    for (int bl = 0; bl < NB; ++bl) {
        int node = s_node[bl];
        float accA = node_emb[(long)node * DD + lane];
        float accB = node_emb[(long)node * DD + lane + 64];
        #pragma unroll
        for (int u = 0; u < UU; ++u) {
            float c = s_comb[bl][u];
            accA += c * wA[u];
            accB += c * wB[u];
        }
        float sq = accA * accA + accB * accB;
        #pragma unroll
        for (int m = 1; m < 64; m <<= 1)
            sq += __shfl_xor(sq, m, 64);
        float invn = 1.f / fmaxf(sqrtf(sq), 1e-12f);
        int ob = (b0 + bl) * (TT * DD) + t * DD;
        out[ob + lane]      = accA * invn;
        out[ob + lane + 64] = accB * invn;
    }
}

extern "C" void kernel_launch(void* const* d_in, const int* in_sizes, int n_in,
                              void* d_out, int out_size, void* d_ws, size_t ws_size,
                              hipStream_t stream) {
    const float* node_emb = (const float*)d_in[0];
    const float* nte_in   = (const float*)d_in[1];
    const float* w        = (const float*)d_in[2];
    const float* s1       = (const float*)d_in[3];
    const float* s2       = (const float*)d_in[4];
    const int* input_nodes  = (const int*)d_in[5];
    const int* output_nodes = (const int*)d_in[6];
    const int* edge_src     = (const int*)d_in[7];
    const int* edge_dst     = (const int*)d_in[8];
    float* out = (float*)d_out;

    // workspace layout
    char* ws = (char*)d_ws;
    float* agg        = (float*)ws;                          // 4 MB
    float* feats      = (float*)(ws + (size_t)AGG_FLOATS*4); // 32 MB
    int*   cnt        = (int*)(ws + (size_t)AGG_FLOATS*4 + (size_t)NSRC*128*4);
    int*   base       = cnt + NBKT;
    int*   cursor     = base + NBKT;
    int*   sortedSrc  = cursor + NBKT;                       // 4 MB
    size_t need = (size_t)AGG_FLOATS*4 + (size_t)NSRC*128*4 + 3u*NBKT*4 + (size_t)NEDGE*4;

    if (ws_size >= need) {
        feats_kernel<<<dim3(NSRC * 32 / 256), dim3(256), 0, stream>>>(
            (const float4*)nte_in, input_nodes, (float4*)feats);
        zero_cnt_kernel<<<dim3(NBKT / 4 / 256), dim3(256), 0, stream>>>((int4*)cnt);
        hist_kernel<<<dim3(NEDGE / 256), dim3(256), 0, stream>>>(edge_dst, cnt);
        scan_kernel<<<dim3(1), dim3(1024), 0, stream>>>(cnt, base, cursor);
        scatter_kernel<<<dim3(NEDGE / 256), dim3(256), 0, stream>>>(
            edge_src, edge_dst, cursor, sortedSrc);
        gather_kernel<<<dim3(NBKT / 4), dim3(256), 0, stream>>>(
            (const float4*)feats, sortedSrc, base, cnt, (float4*)agg);
    } else {
        zero_agg_kernel<<<dim3(AGG_FLOATS / 4 / 256), dim3(256), 0, stream>>>((float4*)agg);
        edge_atomic_kernel<<<dim3((NEDGE * 32) / 256), dim3(256), 0, stream>>>(
            nte_in, input_nodes, edge_src, edge_dst, agg);
    }

    node_kernel<<<dim3(BB / NB), dim3(256), 0, stream>>>(
        node_emb, w, s1, s2, output_nodes, agg, out);
}

// Round 7
// 174.864 us; speedup vs baseline: 1.0433x; 1.0433x over previous
//
#include <hip/hip_runtime.h>
#include <hip/hip_bf16.h>

// Problem constants
#define NUM_NODES 500000
#define DD  128
#define UU  32
#define TT  4
#define AA  32
#define NSRC 65536
#define BB  8192
#define EE  262144                  // = 2^18
#define NEDGE (TT * EE)             // 2^20
#define NBKT (BB * TT)              // 32768 buckets, id = dst*4 + t
#define AGG_FLOATS (BB * TT * UU)   // 1,048,576 floats = 4 MB
#define NB  16                      // output nodes per block in node_kernel

__device__ __forceinline__ unsigned short f2bf(float f) {
    unsigned int u = __float_as_uint(f);
    unsigned int r = (u + 0x7FFFu + ((u >> 16) & 1u)) >> 16;   // RTNE
    return (unsigned short)r;
}

// ------- build per-type bf16 feature slices: feats[t][src][32] bf16 -------
__global__ __launch_bounds__(256) void feats_bf16_kernel(
    const float4* __restrict__ nte4,         // [NUM_NODES][32] float4
    const int* __restrict__ input_nodes,     // [NSRC]
    unsigned short* __restrict__ feats)      // [T][NSRC][32] bf16
{
    int gtid = blockIdx.x * 256 + threadIdx.x;   // T*NSRC*8 threads
    int src = gtid >> 5;
    int t = (gtid >> 3) & 3;
    int q = gtid & 7;
    long node = input_nodes[src];
    float4 v = nte4[node * 32 + t * 8 + q];
    ushort4 o;
    o.x = f2bf(v.x); o.y = f2bf(v.y); o.z = f2bf(v.z); o.w = f2bf(v.w);
    *(ushort4*)(feats + (((size_t)t * NSRC + src) << 5) + (q << 2)) = o;
}

// ---------------- zero int counters ----------------
__global__ __launch_bounds__(256) void zero_cnt_kernel(int4* __restrict__ p) {
    int i = blockIdx.x * 256 + threadIdx.x;   // covers NBKT/4 = 8192
    p[i] = make_int4(0, 0, 0, 0);
}

// ---------------- zero agg (fallback path) ----------------
__global__ __launch_bounds__(256) void zero_agg_kernel(float4* __restrict__ p) {
    int i = blockIdx.x * 256 + threadIdx.x;
    p[i] = make_float4(0.f, 0.f, 0.f, 0.f);
}

// ---------------- histogram of (dst,t) ----------------
__global__ __launch_bounds__(256) void hist_kernel(
    const int* __restrict__ edge_dst, int* __restrict__ cnt)
{
    int i = blockIdx.x * 256 + threadIdx.x;   // edge id in [0, NEDGE)
    int t = i >> 18;                           // E = 2^18
    int dst = edge_dst[i];
    atomicAdd(&cnt[dst * 4 + t], 1);
}

// ---------------- single-block exclusive scan of 32768 counters ----------
__global__ __launch_bounds__(1024) void scan_kernel(
    const int* __restrict__ cnt, int* __restrict__ base, int* __restrict__ cursor)
{
    __shared__ int partial[1024];
    int tid = threadIdx.x;
    int4 v[8];
    const int4* c4 = (const int4*)cnt + tid * 8;
    int s = 0;
    #pragma unroll
    for (int i = 0; i < 8; ++i) {
        v[i] = c4[i];
        s += v[i].x + v[i].y + v[i].z + v[i].w;
    }
    partial[tid] = s;
    __syncthreads();
    for (int off = 1; off < 1024; off <<= 1) {
        int add = (tid >= off) ? partial[tid - off] : 0;
        __syncthreads();
        partial[tid] += add;
        __syncthreads();
    }
    int run = (tid > 0) ? partial[tid - 1] : 0;
    #pragma unroll
    for (int i = 0; i < 8; ++i) {
        int4 b;
        b.x = run; run += v[i].x;
        b.y = run; run += v[i].y;
        b.z = run; run += v[i].z;
        b.w = run; run += v[i].w;
        ((int4*)base)[tid * 8 + i]   = b;
        ((int4*)cursor)[tid * 8 + i] = b;
    }
}

// ---------------- scatter edges into buckets (store src id) --------------
__global__ __launch_bounds__(256) void scatter_kernel(
    const int* __restrict__ edge_src,
    const int* __restrict__ edge_dst,
    int* __restrict__ cursor,
    int* __restrict__ sortedSrc)
{
    int i = blockIdx.x * 256 + threadIdx.x;
    int t = i >> 18;
    int dst = edge_dst[i];
    int pos = atomicAdd(&cursor[dst * 4 + t], 1);
    sortedSrc[pos] = edge_src[i];
}

// -------- gather: wave per bucket, t-grouped for per-XCD L2 residency ----
__global__ __launch_bounds__(256) void gather_kernel(
    const unsigned short* __restrict__ feats,  // [T][NSRC][32] bf16
    const int* __restrict__ sortedSrc,
    const int* __restrict__ base,
    const int* __restrict__ cnt,
    float4* __restrict__ agg4)                 // [B*T][8] float4
{
    int b = blockIdx.x;                 // 8192 blocks
    int xcd = b & 7;                    // blockIdx%8 -> XCD (round-robin)
    int t = xcd >> 1, half = xcd & 1;   // each XCD pair owns one type t
    int wv = threadIdx.x >> 6, lane = threadIdx.x & 63;
    int dst = (b >> 3) * 8 + half * 4 + wv;
    int k = dst * 4 + t;                // bucket id
    int start = base[k], n = cnt[k];
    int pre = min(n, 64);
    int idx = sortedSrc[min(start + lane, NEDGE - 1)];  // coalesced preload
    int e8 = lane >> 3, q = lane & 7;   // edge slot (8/wave), uint2 idx in row
    const uint2* rows = (const uint2*)(feats + ((size_t)t * NSRC << 5)) + q;
    float a0 = 0.f, a1 = 0.f, a2 = 0.f, a3 = 0.f;
    // WAVE-UNIFORM trip count: all 64 lanes iterate nIter times, so every
    // __shfl source lane is active (ds_bpermute from an exited lane is
    // undefined -- that was Round 6's bug). Guard only the accumulate.
    int nIter = (pre + 7) >> 3;
    for (int it = 0; it < nIter; ++it) {
        int j = (it << 3) + e8;
        int s = __shfl(idx, j, 64);
        if (j < pre) {
            uint2 v = rows[(size_t)s * 8];
            a0 += __uint_as_float(v.x << 16);
            a1 += __uint_as_float(v.x & 0xffff0000u);
            a2 += __uint_as_float(v.y << 16);
            a3 += __uint_as_float(v.y & 0xffff0000u);
        }
    }
    for (int j = 64 + e8; j < n; j += 8) {   // rare tail (n > 64), direct loads
        int s = sortedSrc[start + j];
        uint2 v = rows[(size_t)s * 8];
        a0 += __uint_as_float(v.x << 16);
        a1 += __uint_as_float(v.x & 0xffff0000u);
        a2 += __uint_as_float(v.y << 16);
        a3 += __uint_as_float(v.y & 0xffff0000u);
    }
    #pragma unroll
    for (int m = 8; m < 64; m <<= 1) {
        a0 += __shfl_xor(a0, m, 64);
        a1 += __shfl_xor(a1, m, 64);
        a2 += __shfl_xor(a2, m, 64);
        a3 += __shfl_xor(a3, m, 64);
    }
    if (lane < 8) agg4[k * 8 + lane] = make_float4(a0, a1, a2, a3);
}

// ---------------- fallback: direct atomic scatter ------------------------
__global__ __launch_bounds__(256) void edge_atomic_kernel(
    const float* __restrict__ nte_in,
    const int* __restrict__ input_nodes,
    const int* __restrict__ edge_src,
    const int* __restrict__ edge_dst,
    float* __restrict__ agg)
{
    int tid = blockIdx.x * 256 + threadIdx.x;
    int i = tid >> 5;
    int u = tid & 31;
    int t = i >> 18;
    int src = edge_src[i];
    int dst = edge_dst[i];
    int node = input_nodes[src];
    float v = nte_in[(long)node * 128 + t * 32 + u];
    atomicAdd(&agg[dst * 128 + t * 32 + u], v);
}

// ---------------- per-output-node attention + transform ------------------
__global__ __launch_bounds__(256) void node_kernel(
    const float* __restrict__ node_emb,          // [NUM_NODES][D]
    const float* __restrict__ w,                 // [T][U][D]
    const float* __restrict__ s1,                // [T][U][A]
    const float* __restrict__ s2,                // [T][A]
    const int* __restrict__ output_nodes,        // [B]
    const float* __restrict__ agg,               // [B][T][U]
    float* __restrict__ out)                     // [B][T][D]
{
    __shared__ float s_nte[NB][TT * UU];
    __shared__ float s_comb[NB][UU];
    __shared__ float s_sc[NB][TT];
    __shared__ int   s_node[NB];

    int tid  = threadIdx.x;
    int wv   = tid >> 6;
    int lane = tid & 63;
    int b0   = blockIdx.x * NB;

    {
        const float4* av = (const float4*)(agg + b0 * 128);
        float4* sv = (float4*)&s_nte[0][0];
        sv[tid]       = av[tid];
        sv[tid + 256] = av[tid + 256];
    }
    if (tid < NB) s_node[tid] = output_nodes[b0 + tid];
    __syncthreads();

    // ---- Phase A: attention scores ----
    int a  = lane & 31;
    int th = lane >> 5;
    int t0 = th, t1 = th + 2;
    float s1a[UU], s1b[UU];
    #pragma unroll
    for (int u = 0; u < UU; ++u) {
        s1a[u] = s1[(t0 * UU + u) * AA + a];
        s1b[u] = s1[(t1 * UU + u) * AA + a];
    }
    float s2a = s2[t0 * AA + a];
    float s2b = s2[t1 * AA + a];

    #pragma unroll
    for (int q = 0; q < 4; ++q) {
        int bl = wv * 4 + q;
        float acc0 = 0.f, acc1 = 0.f;
        #pragma unroll
        for (int u = 0; u < UU; ++u) {
            acc0 += s_nte[bl][t0 * UU + u] * s1a[u];
            acc1 += s_nte[bl][t1 * UU + u] * s1b[u];
        }
        float p0 = tanhf(acc0) * s2a;
        float p1 = tanhf(acc1) * s2b;
        #pragma unroll
        for (int m = 1; m < 32; m <<= 1) {
            p0 += __shfl_xor(p0, m, 64);
            p1 += __shfl_xor(p1, m, 64);
        }
        if ((lane & 31) == 0) { s_sc[bl][th] = p0; s_sc[bl][th + 2] = p1; }
    }
    __syncthreads();

    #pragma unroll
    for (int q = 0; q < 4; ++q) {
        int bl = wv * 4 + q;
        float sc0 = s_sc[bl][0], sc1 = s_sc[bl][1];
        float sc2 = s_sc[bl][2], sc3 = s_sc[bl][3];
        float mx = fmaxf(fmaxf(sc0, sc1), fmaxf(sc2, sc3));
        float e0 = expf(sc0 - mx), e1 = expf(sc1 - mx);
        float e2 = expf(sc2 - mx), e3 = expf(sc3 - mx);
        float isum = 1.f / (e0 + e1 + e2 + e3);
        if (lane < 32) {
            float c = e0 * isum * s_nte[bl][a]
                    + e1 * isum * s_nte[bl][UU + a]
                    + e2 * isum * s_nte[bl][2 * UU + a]
                    + e3 * isum * s_nte[bl][3 * UU + a];
            s_comb[bl][a] = c;
        }
    }
    __syncthreads();

    // ---- Phase B: transform + add emb + normalize; wave == t ----
    int t = wv;
    const float* wt = w + t * (UU * DD);
    float wA[UU], wB[UU];
    #pragma unroll
    for (int u = 0; u < UU; ++u) {
        wA[u] = wt[u * DD + lane];
        wB[u] = wt[u * DD + lane + 64];
    }
    for (int bl = 0; bl < NB; ++bl) {
        int node = s_node[bl];
        float accA = node_emb[(long)node * DD + lane];
        float accB = node_emb[(long)node * DD + lane + 64];
        #pragma unroll
        for (int u = 0; u < UU; ++u) {
            float c = s_comb[bl][u];
            accA += c * wA[u];
            accB += c * wB[u];
        }
        float sq = accA * accA + accB * accB;
        #pragma unroll
        for (int m = 1; m < 64; m <<= 1)
            sq += __shfl_xor(sq, m, 64);
        float invn = 1.f / fmaxf(sqrtf(sq), 1e-12f);
        int ob = (b0 + bl) * (TT * DD) + t * DD;
        out[ob + lane]      = accA * invn;
        out[ob + lane + 64] = accB * invn;
    }
}

extern "C" void kernel_launch(void* const* d_in, const int* in_sizes, int n_in,
                              void* d_out, int out_size, void* d_ws, size_t ws_size,
                              hipStream_t stream) {
    const float* node_emb = (const float*)d_in[0];
    const float* nte_in   = (const float*)d_in[1];
    const float* w        = (const float*)d_in[2];
    const float* s1       = (const float*)d_in[3];
    const float* s2       = (const float*)d_in[4];
    const int* input_nodes  = (const int*)d_in[5];
    const int* output_nodes = (const int*)d_in[6];
    const int* edge_src     = (const int*)d_in[7];
    const int* edge_dst     = (const int*)d_in[8];
    float* out = (float*)d_out;

    // workspace layout
    char* ws = (char*)d_ws;
    float*          agg   = (float*)ws;                                  // 4 MB
    unsigned short* feats = (unsigned short*)(ws + (size_t)AGG_FLOATS*4);// 16 MB
    char* p2 = ws + (size_t)AGG_FLOATS*4 + (size_t)TT*NSRC*32*2;
    int*   cnt        = (int*)p2;                                        // 128 KB
    int*   base       = cnt + NBKT;
    int*   cursor     = base + NBKT;
    int*   sortedSrc  = cursor + NBKT;                                   // 4 MB
    size_t need = (size_t)AGG_FLOATS*4 + (size_t)TT*NSRC*32*2 + 3u*NBKT*4
                + (size_t)NEDGE*4;

    if (ws_size >= need) {
        feats_bf16_kernel<<<dim3(TT * NSRC * 8 / 256), dim3(256), 0, stream>>>(
            (const float4*)nte_in, input_nodes, feats);
        zero_cnt_kernel<<<dim3(NBKT / 4 / 256), dim3(256), 0, stream>>>((int4*)cnt);
        hist_kernel<<<dim3(NEDGE / 256), dim3(256), 0, stream>>>(edge_dst, cnt);
        scan_kernel<<<dim3(1), dim3(1024), 0, stream>>>(cnt, base, cursor);
        scatter_kernel<<<dim3(NEDGE / 256), dim3(256), 0, stream>>>(
            edge_src, edge_dst, cursor, sortedSrc);
        gather_kernel<<<dim3(BB), dim3(256), 0, stream>>>(
            feats, sortedSrc, base, cnt, (float4*)agg);
    } else {
        zero_agg_kernel<<<dim3(AGG_FLOATS / 4 / 256), dim3(256), 0, stream>>>((float4*)agg);
        edge_atomic_kernel<<<dim3((NEDGE * 32) / 256), dim3(256), 0, stream>>>(
            nte_in, input_nodes, edge_src, edge_dst, agg);
    }

    node_kernel<<<dim3(BB / NB), dim3(256), 0, stream>>>(
        node_emb, w, s1, s2, output_nodes, agg, out);
}